// Round 1
// baseline (216.436 us; speedup 1.0000x reference)
//
#include <hip/hip_runtime.h>
#include <hip/hip_bf16.h>
#include <cstdint>

#define QLEN   1024
#define KLEN   2048
#define DMODEL 2048
#define BATCH  4
#define FLEN   (KLEN - QLEN + 1)   // 1025

typedef __bf16 bf16x8 __attribute__((ext_vector_type(8)));
typedef __bf16 bf16x4 __attribute__((ext_vector_type(4)));
typedef float  f32x4  __attribute__((ext_vector_type(4)));

// Static device scratch (avoids any ws_size assumptions).
__device__ __bf16 g_ft[(size_t)QLEN * KLEN];          // FT, scale baked, bf16 (4 MB)
__device__ __bf16 g_yt[(size_t)BATCH * DMODEL * KLEN]; // y^T = (x+p)^T per batch (33.5 MB)

// ---------------- FT generation ----------------
// FT[l,m] = cos(2*pi*((l*(m-l)) % 1025)/1025) / sqrt(1025*2048) inside band l<=m<=l+1024.
__global__ void gen_ft_kernel() {
  const int idx = blockIdx.x * 256 + threadIdx.x;   // over QLEN*KLEN
  const int l = idx >> 11;          // / KLEN
  const int m = idx & (KLEN - 1);
  const int j = m - l;
  float v = 0.0f;
  if (j >= 0 && j < FLEN) {
    const int r = (l * j) % FLEN;                   // exact integer phase reduction
    const float w = 6.283185307179586f / (float)FLEN;
    const float scale = 1.0f / sqrtf((float)FLEN * (float)KLEN);
    v = cosf((float)r * w) * scale;
  }
  g_ft[idx] = (__bf16)v;
}

// ---------------- y^T generation (add + cast + transpose) ----------------
// yt[b][d][m] = bf16(x[b][m][d] + p[b][m][d])  (p added iff add_position)
__global__ void gen_yt_kernel(const float* __restrict__ x, const float* __restrict__ p,
                              const int* __restrict__ addp) {
  __shared__ float tile[64][65];                    // +1 pad breaks transpose conflicts
  const int b  = blockIdx.z;
  const int m0 = blockIdx.x * 64;
  const int d0 = blockIdx.y * 64;
  const int t  = threadIdx.x;                       // 256 threads
  const int add = *addp;
  const size_t base = (size_t)b * KLEN * DMODEL;
  const int rr = t >> 4;          // 0..15
  const int cc = (t & 15) * 4;    // 0..60
#pragma unroll
  for (int it = 0; it < 4; ++it) {
    const int r = rr + it * 16;
    const size_t off = base + (size_t)(m0 + r) * DMODEL + (d0 + cc);
    float4 v = *(const float4*)(x + off);
    if (add) {
      const float4 pv = *(const float4*)(p + off);
      v.x += pv.x; v.y += pv.y; v.z += pv.z; v.w += pv.w;
    }
    tile[r][cc + 0] = v.x; tile[r][cc + 1] = v.y;
    tile[r][cc + 2] = v.z; tile[r][cc + 3] = v.w;
  }
  __syncthreads();
#pragma unroll
  for (int it = 0; it < 4; ++it) {
    const int d = rr + it * 16;
    bf16x4 o;
    o[0] = (__bf16)tile[cc + 0][d];
    o[1] = (__bf16)tile[cc + 1][d];
    o[2] = (__bf16)tile[cc + 2][d];
    o[3] = (__bf16)tile[cc + 3][d];
    *(bf16x4*)(g_yt + base + (size_t)(d0 + d) * KLEN + (m0 + cc)) = o;
  }
}

// ---------------- GEMM: out[b][l][d] = sum_m FT[l][m] * yt[b][d][m] ----------------
#define BM 128
#define BN 128
#define BK 64

typedef __attribute__((address_space(1))) void gvoid;
typedef __attribute__((address_space(3))) void svoid;

__device__ __forceinline__ void async_load16(const void* g, void* lds) {
  gvoid* gp = (gvoid*)(uintptr_t)g;
  svoid* sp = (svoid*)(uint32_t)(uintptr_t)lds;   // flat LDS addr low 32 bits == LDS offset
  __builtin_amdgcn_global_load_lds(gp, sp, 16, 0, 0);
}

__global__ __launch_bounds__(256) void gemm_kernel(float* __restrict__ out) {
  // grid: (DMODEL/BN, QLEN/BM, BATCH); 4 waves; wave tile 64x64 (4x4 of 16x16x32 MFMA)
  __shared__ __align__(16) __bf16 As[BM * BK];   // [l'][k'] chunk-swizzled, 16 KB
  __shared__ __align__(16) __bf16 Bs[BN * BK];   // [d'][k'] chunk-swizzled, 16 KB
  const int bn = blockIdx.x, bm = blockIdx.y, b = blockIdx.z;
  const int l0 = bm * BM, d0 = bn * BN;
  const int tid  = threadIdx.x;
  const int lane = tid & 63;
  const int wave = tid >> 6;
  const int wr = wave >> 1, wc = wave & 1;
  const int col = lane & 15, quad = lane >> 4;

  f32x4 acc[4][4] = {};

  // band: FT[l,m] nonzero only for l <= m <= l+1024 -> K-tiles [l0/64, (l0+1151)/64]
  const int t0 = l0 >> 6;
  const int t1 = (l0 + BM - 1 + FLEN - 1) >> 6;   // inclusive; 18 tiles
  const __bf16* ftp = g_ft;
  const __bf16* ytp = g_yt + (size_t)b * DMODEL * KLEN;

  for (int t = t0; t <= t1; ++t) {
    const int k0 = t * BK;
    // Stage A (FT) and B (y^T): both 128 rows x 64 k, row-major, 8x16B chunks/row.
    // XOR swizzle applied on GLOBAL side: LDS chunk (row, sc8) holds global chunk
    // (row, sc8 ^ (row&7)), since global_load_lds writes lane i at base + i*16.
#pragma unroll
    for (int s = 0; s < 4; ++s) {
      const int cb  = wave * 256 + s * 64;
      const int lc  = cb + lane;
      const int row = lc >> 3;
      const int gc8 = (lc & 7) ^ (row & 7);
      async_load16(ftp + (size_t)(l0 + row) * KLEN + k0 + gc8 * 8, As + cb * 8);
    }
#pragma unroll
    for (int s = 0; s < 4; ++s) {
      const int cb  = wave * 256 + s * 64;
      const int lc  = cb + lane;
      const int row = lc >> 3;
      const int gc8 = (lc & 7) ^ (row & 7);
      async_load16(ytp + (size_t)(d0 + row) * KLEN + k0 + gc8 * 8, Bs + cb * 8);
    }
    __syncthreads();   // drains vmcnt -> staged data visible

#pragma unroll
    for (int kk = 0; kk < 2; ++kk) {
      bf16x8 af[4], bq[4];
      const int c8 = kk * 4 + quad;
#pragma unroll
      for (int ti = 0; ti < 4; ++ti) {
        const int r = wr * 64 + ti * 16 + col;            // A row (l), frag m = lane&15
        af[ti] = *(const bf16x8*)(As + (size_t)((r << 3) + (c8 ^ (r & 7))) * 8);
      }
#pragma unroll
      for (int tj = 0; tj < 4; ++tj) {
        const int r = wc * 64 + tj * 16 + col;            // B row (d), frag n = lane&15
        bq[tj] = *(const bf16x8*)(Bs + (size_t)((r << 3) + (c8 ^ (r & 7))) * 8);
      }
#pragma unroll
      for (int ti = 0; ti < 4; ++ti)
#pragma unroll
        for (int tj = 0; tj < 4; ++tj)
          acc[ti][tj] = __builtin_amdgcn_mfma_f32_16x16x32_bf16(af[ti], bq[tj], acc[ti][tj], 0, 0, 0);
    }
    __syncthreads();   // protect LDS from next iteration's staging
  }

  // Epilogue: C/D layout col = lane&15, row = quad*4 + reg  [m89/m91 verified]
#pragma unroll
  for (int ti = 0; ti < 4; ++ti) {
    const int l = l0 + wr * 64 + ti * 16 + quad * 4;
#pragma unroll
    for (int tj = 0; tj < 4; ++tj) {
      const int d = d0 + wc * 64 + tj * 16 + col;
      float* op = out + (size_t)b * QLEN * DMODEL + (size_t)l * DMODEL + d;
#pragma unroll
      for (int r2 = 0; r2 < 4; ++r2) op[(size_t)r2 * DMODEL] = acc[ti][tj][r2];
    }
  }
}

extern "C" void kernel_launch(void* const* d_in, const int* in_sizes, int n_in,
                              void* d_out, int out_size, void* d_ws, size_t ws_size,
                              hipStream_t stream) {
  const float* x   = (const float*)d_in[0];
  const float* p   = (const float*)d_in[1];
  const int* addp  = (const int*)d_in[3];   // add_position (qlen fixed at 1024 by shapes)
  float* out = (float*)d_out;

  gen_ft_kernel<<<dim3((QLEN * KLEN) / 256), dim3(256), 0, stream>>>();
  gen_yt_kernel<<<dim3(KLEN / 64, DMODEL / 64, BATCH), dim3(256), 0, stream>>>(x, p, addp);
  gemm_kernel<<<dim3(DMODEL / BN, QLEN / BM, BATCH), dim3(256), 0, stream>>>(out);
}

// Round 2
// 207.522 us; speedup vs baseline: 1.0430x; 1.0430x over previous
//
#include <hip/hip_runtime.h>
#include <hip/hip_bf16.h>
#include <cstdint>

#define QLEN   1024
#define KLEN   2048
#define DMODEL 2048
#define BATCH  4
#define FLEN   (KLEN - QLEN + 1)   // 1025

typedef __bf16 bf16x8 __attribute__((ext_vector_type(8)));
typedef __bf16 bf16x4 __attribute__((ext_vector_type(4)));
typedef float  f32x4  __attribute__((ext_vector_type(4)));

// Static device scratch.
__device__ __bf16 g_ft[(size_t)QLEN * KLEN];           // FT, scale baked, bf16 (4 MB)
__device__ __bf16 g_yt[(size_t)BATCH * DMODEL * KLEN]; // y^T = (x+p)^T per batch (33.5 MB)

// ---------------- FT generation ----------------
// FT[l,m] = cos(2*pi*((l*(m-l)) % 1025)/1025) / sqrt(1025*2048) inside band l<=m<=l+1024.
// 8 elements (consecutive m, same l) per thread, single 16B store; whole-chunk
// out-of-band rows short-circuit to a zero store.
__global__ void gen_ft_kernel() {
  const int u  = blockIdx.x * 256 + threadIdx.x;  // over QLEN*KLEN/8
  const int l  = u >> 8;                          // KLEN/8 = 256 chunks per row
  const int m0 = (u & 255) * 8;
  const int j0 = m0 - l;
  bf16x8 o = {};
  if (j0 + 7 >= 0 && j0 < FLEN) {
    const float w     = 6.283185307179586f / (float)FLEN;
    const float scale = 1.0f / sqrtf((float)FLEN * (float)KLEN);
#pragma unroll
    for (int i = 0; i < 8; ++i) {
      const int j = j0 + i;
      float v = 0.0f;
      if (j >= 0 && j < FLEN) {
        const int r = (l * j) % FLEN;             // exact: l*j < 2^20, magic-mul mod
        v = cosf((float)r * w) * scale;
      }
      o[i] = (__bf16)v;
    }
  }
  *(bf16x8*)(g_ft + (size_t)u * 8) = o;
}

// ---------------- y^T generation (add + cast + transpose) ----------------
// yt[b][d][m] = bf16(x[b][m][d] + addf*p[b][m][d])
// Key fix vs round 1: ALL 8 float4 loads are issued into register arrays before
// any LDS write (round-1 codegen had VGPR_Count=12 -> MLP~1 -> 1.5 TB/s).
__global__ void gen_yt_kernel(const float* __restrict__ x, const float* __restrict__ p,
                              const int* __restrict__ addp) {
  __shared__ float tile[64][65];                  // (m+d)%32 banking -> 2-way max (free)
  const int b  = blockIdx.z;
  const int m0 = blockIdx.x * 64;
  const int d0 = blockIdx.y * 64;
  const int t  = threadIdx.x;                     // 256 threads
  const float addf = (*addp) ? 1.0f : 0.0f;
  const size_t base = (size_t)b * KLEN * DMODEL;

  // Phase 1: load 64x64 fp32 tile, rows m, cols d. Thread t covers rows
  // r = (t>>4) + 16*it, cols c4 = (t&15)*4 (float4).
  const int rr = t >> 4;
  const int c4 = (t & 15) * 4;
  float4 xv[4], pv[4];
#pragma unroll
  for (int it = 0; it < 4; ++it) {
    const size_t off = base + (size_t)(m0 + rr + it * 16) * DMODEL + (d0 + c4);
    xv[it] = *(const float4*)(x + off);
  }
#pragma unroll
  for (int it = 0; it < 4; ++it) {
    const size_t off = base + (size_t)(m0 + rr + it * 16) * DMODEL + (d0 + c4);
    pv[it] = *(const float4*)(p + off);
  }
#pragma unroll
  for (int it = 0; it < 4; ++it) {
    const int r = rr + it * 16;
    tile[r][c4 + 0] = xv[it].x + addf * pv[it].x;
    tile[r][c4 + 1] = xv[it].y + addf * pv[it].y;
    tile[r][c4 + 2] = xv[it].z + addf * pv[it].z;
    tile[r][c4 + 3] = xv[it].w + addf * pv[it].w;
  }
  __syncthreads();

  // Phase 2: each unit u = t + 256*s handles (d = u>>3, m-chunk mc = u&7):
  // pack 8 consecutive m into one bf16x8 -> 16B store. LDS read bank =
  // (8*mc + i + d)%32 -> 2-way max (free). Store: 8 lanes x 16B = 128B rows.
#pragma unroll
  for (int s = 0; s < 2; ++s) {
    const int u  = t + 256 * s;
    const int d  = u >> 3;
    const int mc = u & 7;
    bf16x8 o;
#pragma unroll
    for (int i = 0; i < 8; ++i) o[i] = (__bf16)tile[mc * 8 + i][d];
    *(bf16x8*)(g_yt + base + (size_t)(d0 + d) * KLEN + (m0 + mc * 8)) = o;
  }
}

// ---------------- GEMM: out[b][l][d] = sum_m FT[l][m] * yt[b][d][m] ----------------
#define BM 128
#define BN 128
#define BK 64

typedef __attribute__((address_space(1))) void gvoid;
typedef __attribute__((address_space(3))) void svoid;

__device__ __forceinline__ void async_load16(const void* g, void* lds) {
  gvoid* gp = (gvoid*)(uintptr_t)g;
  svoid* sp = (svoid*)(uint32_t)(uintptr_t)lds;   // flat LDS addr low 32 bits == LDS offset
  __builtin_amdgcn_global_load_lds(gp, sp, 16, 0, 0);
}

__global__ __launch_bounds__(256) void gemm_kernel(float* __restrict__ out) {
  // grid: (DMODEL/BN, QLEN/BM, BATCH); 4 waves; wave tile 64x64 (4x4 of 16x16x32 MFMA)
  __shared__ __align__(16) __bf16 As[BM * BK];   // [l'][k'] chunk-swizzled, 16 KB
  __shared__ __align__(16) __bf16 Bs[BN * BK];   // [d'][k'] chunk-swizzled, 16 KB
  const int bn = blockIdx.x, bm = blockIdx.y, b = blockIdx.z;
  const int l0 = bm * BM, d0 = bn * BN;
  const int tid  = threadIdx.x;
  const int lane = tid & 63;
  const int wave = tid >> 6;
  const int wr = wave >> 1, wc = wave & 1;
  const int col = lane & 15, quad = lane >> 4;

  f32x4 acc[4][4] = {};

  // band: FT[l,m] nonzero only for l <= m <= l+1024 -> K-tiles [l0/64, (l0+1151)/64]
  const int t0 = l0 >> 6;
  const int t1 = (l0 + BM - 1 + FLEN - 1) >> 6;   // inclusive; 18 tiles
  const __bf16* ftp = g_ft;
  const __bf16* ytp = g_yt + (size_t)b * DMODEL * KLEN;

  for (int t = t0; t <= t1; ++t) {
    const int k0 = t * BK;
    // Stage A (FT) and B (y^T): both 128 rows x 64 k, row-major, 8x16B chunks/row.
    // XOR swizzle applied on GLOBAL side: LDS chunk (row, sc8) holds global chunk
    // (row, sc8 ^ (row&7)), since global_load_lds writes lane i at base + i*16.
#pragma unroll
    for (int s = 0; s < 4; ++s) {
      const int cb  = wave * 256 + s * 64;
      const int lc  = cb + lane;
      const int row = lc >> 3;
      const int gc8 = (lc & 7) ^ (row & 7);
      async_load16(ftp + (size_t)(l0 + row) * KLEN + k0 + gc8 * 8, As + cb * 8);
    }
#pragma unroll
    for (int s = 0; s < 4; ++s) {
      const int cb  = wave * 256 + s * 64;
      const int lc  = cb + lane;
      const int row = lc >> 3;
      const int gc8 = (lc & 7) ^ (row & 7);
      async_load16(ytp + (size_t)(d0 + row) * KLEN + k0 + gc8 * 8, Bs + cb * 8);
    }
    __syncthreads();   // drains vmcnt -> staged data visible

#pragma unroll
    for (int kk = 0; kk < 2; ++kk) {
      bf16x8 af[4], bq[4];
      const int c8 = kk * 4 + quad;
#pragma unroll
      for (int ti = 0; ti < 4; ++ti) {
        const int r = wr * 64 + ti * 16 + col;            // A row (l), frag m = lane&15
        af[ti] = *(const bf16x8*)(As + (size_t)((r << 3) + (c8 ^ (r & 7))) * 8);
      }
#pragma unroll
      for (int tj = 0; tj < 4; ++tj) {
        const int r = wc * 64 + tj * 16 + col;            // B row (d), frag n = lane&15
        bq[tj] = *(const bf16x8*)(Bs + (size_t)((r << 3) + (c8 ^ (r & 7))) * 8);
      }
#pragma unroll
      for (int ti = 0; ti < 4; ++ti)
#pragma unroll
        for (int tj = 0; tj < 4; ++tj)
          acc[ti][tj] = __builtin_amdgcn_mfma_f32_16x16x32_bf16(af[ti], bq[tj], acc[ti][tj], 0, 0, 0);
    }
    __syncthreads();   // protect LDS from next iteration's staging
  }

  // Epilogue: C/D layout col = lane&15, row = quad*4 + reg  [m89/m91 verified]
#pragma unroll
  for (int ti = 0; ti < 4; ++ti) {
    const int l = l0 + wr * 64 + ti * 16 + quad * 4;
#pragma unroll
    for (int tj = 0; tj < 4; ++tj) {
      const int d = d0 + wc * 64 + tj * 16 + col;
      float* op = out + (size_t)b * QLEN * DMODEL + (size_t)l * DMODEL + d;
#pragma unroll
      for (int r2 = 0; r2 < 4; ++r2) op[(size_t)r2 * DMODEL] = acc[ti][tj][r2];
    }
  }
}

extern "C" void kernel_launch(void* const* d_in, const int* in_sizes, int n_in,
                              void* d_out, int out_size, void* d_ws, size_t ws_size,
                              hipStream_t stream) {
  const float* x   = (const float*)d_in[0];
  const float* p   = (const float*)d_in[1];
  const int* addp  = (const int*)d_in[3];   // add_position (qlen fixed at 1024 by shapes)
  float* out = (float*)d_out;

  gen_ft_kernel<<<dim3((QLEN * KLEN / 8) / 256), dim3(256), 0, stream>>>();
  gen_yt_kernel<<<dim3(KLEN / 64, DMODEL / 64, BATCH), dim3(256), 0, stream>>>(x, p, addp);
  gemm_kernel<<<dim3(DMODEL / BN, QLEN / BM, BATCH), dim3(256), 0, stream>>>(out);
}

// Round 3
// 206.174 us; speedup vs baseline: 1.0498x; 1.0065x over previous
//
#include <hip/hip_runtime.h>
#include <hip/hip_bf16.h>
#include <cstdint>

#define QLEN   1024
#define KLEN   2048
#define DMODEL 2048
#define BATCH  4
#define FLEN   (KLEN - QLEN + 1)   // 1025

typedef __bf16 bf16x8 __attribute__((ext_vector_type(8)));
typedef __bf16 bf16x4 __attribute__((ext_vector_type(4)));
typedef float  f32x4  __attribute__((ext_vector_type(4)));

// Static device scratch.
__device__ __bf16 g_ft[(size_t)QLEN * KLEN];           // FT, scale baked, bf16 (4 MB)
__device__ __bf16 g_yt[(size_t)BATCH * DMODEL * KLEN]; // y^T = (x+p)^T per batch (33.5 MB)

typedef __attribute__((address_space(1))) void gvoid;
typedef __attribute__((address_space(3))) void svoid;

__device__ __forceinline__ void async_load16(const void* g, void* lds) {
  gvoid* gp = (gvoid*)(uintptr_t)g;
  svoid* sp = (svoid*)(uint32_t)(uintptr_t)lds;   // flat LDS addr low 32 bits == LDS offset
  __builtin_amdgcn_global_load_lds(gp, sp, 16, 0, 0);
}

// ---------------- FT generation ----------------
// FT[l,m] = cos(2*pi*((l*(m-l)) % 1025)/1025) / sqrt(1025*2048) inside band l<=m<=l+1024.
__global__ void gen_ft_kernel() {
  const int u  = blockIdx.x * 256 + threadIdx.x;  // over QLEN*KLEN/8
  const int l  = u >> 8;                          // KLEN/8 = 256 chunks per row
  const int m0 = (u & 255) * 8;
  const int j0 = m0 - l;
  bf16x8 o = {};
  if (j0 + 7 >= 0 && j0 < FLEN) {
    const float w     = 6.283185307179586f / (float)FLEN;
    const float scale = 1.0f / sqrtf((float)FLEN * (float)KLEN);
#pragma unroll
    for (int i = 0; i < 8; ++i) {
      const int j = j0 + i;
      float v = 0.0f;
      if (j >= 0 && j < FLEN) {
        const int r = (l * j) % FLEN;             // exact: l*j < 2^20, magic-mul mod
        v = cosf((float)r * w) * scale;
      }
      o[i] = (__bf16)v;
    }
  }
  *(bf16x8*)(g_ft + (size_t)u * 8) = o;
}

// ---------------- y^T generation (add + cast + transpose) ----------------
// yt[b][d][m] = bf16(x[b][m][d] + addf*p[b][m][d])
// Round-3 fix: stage x/p tiles via async global_load_lds — data bypasses VGPRs,
// so the register allocator CANNOT serialize the loads (rounds 1-2 pathology:
// VGPR_Count 12/28 -> MLP~1 -> 1.6 TB/s, VALUBusy 2.4%).
// Swizzle: LDS chunk (m, c) holds global chunk (m, c ^ ((m>>3)&7)). Phase-2
// transposed reads then hit exactly 2 lanes/bank (free, m136).
__global__ __launch_bounds__(256) void gen_yt_kernel(const float* __restrict__ x,
                                                     const float* __restrict__ p,
                                                     const int* __restrict__ addp) {
  __shared__ __align__(16) float xt[64 * 64];     // 16 KB, rows m (64 floats), swizzled
  __shared__ __align__(16) float pt[64 * 64];     // 16 KB
  const int b  = blockIdx.z;
  const int m0 = blockIdx.x * 64;
  const int d0 = blockIdx.y * 64;
  const int t  = threadIdx.x;                     // 256 threads = 4 waves
  const int lane = t & 63;
  const int wave = t >> 6;
  const float addf = (*addp) ? 1.0f : 0.0f;
  const size_t base = (size_t)b * KLEN * DMODEL;

  // Phase 1: async-stage both 64x64 fp32 tiles. 4 sweeps/tile x 4 waves x 64
  // lanes x 16B. All 8 global_load_lds per thread issue back-to-back (MLP=8).
#pragma unroll
  for (int q = 0; q < 4; ++q) {
    const int cb = q * 256 + wave * 64;           // wave-uniform chunk base
    const int fc = cb + lane;                     // this lane's LDS chunk
    const int m  = fc >> 4;                       // 16 chunks (64 floats) per row
    const int cl = fc & 15;
    const int gc = cl ^ ((m >> 3) & 7);           // global-side XOR swizzle
    async_load16(x + base + (size_t)(m0 + m) * DMODEL + d0 + gc * 4, xt + cb * 4);
  }
#pragma unroll
  for (int q = 0; q < 4; ++q) {
    const int cb = q * 256 + wave * 64;
    const int fc = cb + lane;
    const int m  = fc >> 4;
    const int cl = fc & 15;
    const int gc = cl ^ ((m >> 3) & 7);
    async_load16(p + base + (size_t)(m0 + m) * DMODEL + d0 + gc * 4, pt + cb * 4);
  }
  __syncthreads();   // drains vmcnt -> staged data visible

  // Phase 2: unit u -> (d = u>>3, mc = u&7); pack 8 consecutive m -> 16B store.
  // LDS dword for (m, d): m*64 + 4*((d>>2) ^ mc) + (d&3); exactly 2-way banked.
#pragma unroll
  for (int s = 0; s < 2; ++s) {
    const int u  = t + 256 * s;
    const int d  = u >> 3;
    const int mc = u & 7;
    bf16x8 o;
#pragma unroll
    for (int i = 0; i < 8; ++i) {
      const int idx = (mc * 8 + i) * 64 + 4 * ((d >> 2) ^ mc) + (d & 3);
      o[i] = (__bf16)(xt[idx] + addf * pt[idx]);
    }
    *(bf16x8*)(g_yt + base + (size_t)(d0 + d) * KLEN + (m0 + mc * 8)) = o;
  }
}

// ---------------- GEMM: out[b][l][d] = sum_m FT[l][m] * yt[b][d][m] ----------------
#define BM 128
#define BN 128
#define BK 64

__global__ __launch_bounds__(256) void gemm_kernel(float* __restrict__ out) {
  // grid: (DMODEL/BN, QLEN/BM, BATCH); 4 waves; wave tile 64x64 (4x4 of 16x16x32 MFMA)
  __shared__ __align__(16) __bf16 As[BM * BK];   // [l'][k'] chunk-swizzled, 16 KB
  __shared__ __align__(16) __bf16 Bs[BN * BK];   // [d'][k'] chunk-swizzled, 16 KB
  const int bn = blockIdx.x, bm = blockIdx.y, b = blockIdx.z;
  const int l0 = bm * BM, d0 = bn * BN;
  const int tid  = threadIdx.x;
  const int lane = tid & 63;
  const int wave = tid >> 6;
  const int wr = wave >> 1, wc = wave & 1;
  const int col = lane & 15, quad = lane >> 4;

  f32x4 acc[4][4] = {};

  // band: FT[l,m] nonzero only for l <= m <= l+1024 -> K-tiles [l0/64, (l0+1151)/64]
  const int t0 = l0 >> 6;
  const int t1 = (l0 + BM - 1 + FLEN - 1) >> 6;   // inclusive; 18 tiles
  const __bf16* ftp = g_ft;
  const __bf16* ytp = g_yt + (size_t)b * DMODEL * KLEN;

  for (int t = t0; t <= t1; ++t) {
    const int k0 = t * BK;
    // Stage A (FT) and B (y^T): both 128 rows x 64 k, row-major, 8x16B chunks/row.
    // XOR swizzle applied on GLOBAL side: LDS chunk (row, sc8) holds global chunk
    // (row, sc8 ^ (row&7)), since global_load_lds writes lane i at base + i*16.
#pragma unroll
    for (int s = 0; s < 4; ++s) {
      const int cb  = wave * 256 + s * 64;
      const int lc  = cb + lane;
      const int row = lc >> 3;
      const int gc8 = (lc & 7) ^ (row & 7);
      async_load16(ftp + (size_t)(l0 + row) * KLEN + k0 + gc8 * 8, As + cb * 8);
    }
#pragma unroll
    for (int s = 0; s < 4; ++s) {
      const int cb  = wave * 256 + s * 64;
      const int lc  = cb + lane;
      const int row = lc >> 3;
      const int gc8 = (lc & 7) ^ (row & 7);
      async_load16(ytp + (size_t)(d0 + row) * KLEN + k0 + gc8 * 8, Bs + cb * 8);
    }
    __syncthreads();   // drains vmcnt -> staged data visible

#pragma unroll
    for (int kk = 0; kk < 2; ++kk) {
      bf16x8 af[4], bq[4];
      const int c8 = kk * 4 + quad;
#pragma unroll
      for (int ti = 0; ti < 4; ++ti) {
        const int r = wr * 64 + ti * 16 + col;            // A row (l), frag m = lane&15
        af[ti] = *(const bf16x8*)(As + (size_t)((r << 3) + (c8 ^ (r & 7))) * 8);
      }
#pragma unroll
      for (int tj = 0; tj < 4; ++tj) {
        const int r = wc * 64 + tj * 16 + col;            // B row (d), frag n = lane&15
        bq[tj] = *(const bf16x8*)(Bs + (size_t)((r << 3) + (c8 ^ (r & 7))) * 8);
      }
#pragma unroll
      for (int ti = 0; ti < 4; ++ti)
#pragma unroll
        for (int tj = 0; tj < 4; ++tj)
          acc[ti][tj] = __builtin_amdgcn_mfma_f32_16x16x32_bf16(af[ti], bq[tj], acc[ti][tj], 0, 0, 0);
    }
    __syncthreads();   // protect LDS from next iteration's staging
  }

  // Epilogue: C/D layout col = lane&15, row = quad*4 + reg  [m89/m91 verified]
#pragma unroll
  for (int ti = 0; ti < 4; ++ti) {
    const int l = l0 + wr * 64 + ti * 16 + quad * 4;
#pragma unroll
    for (int tj = 0; tj < 4; ++tj) {
      const int d = d0 + wc * 64 + tj * 16 + col;
      float* op = out + (size_t)b * QLEN * DMODEL + (size_t)l * DMODEL + d;
#pragma unroll
      for (int r2 = 0; r2 < 4; ++r2) op[(size_t)r2 * DMODEL] = acc[ti][tj][r2];
    }
  }
}

extern "C" void kernel_launch(void* const* d_in, const int* in_sizes, int n_in,
                              void* d_out, int out_size, void* d_ws, size_t ws_size,
                              hipStream_t stream) {
  const float* x   = (const float*)d_in[0];
  const float* p   = (const float*)d_in[1];
  const int* addp  = (const int*)d_in[3];   // add_position (qlen fixed at 1024 by shapes)
  float* out = (float*)d_out;

  gen_ft_kernel<<<dim3((QLEN * KLEN / 8) / 256), dim3(256), 0, stream>>>();
  gen_yt_kernel<<<dim3(KLEN / 64, DMODEL / 64, BATCH), dim3(256), 0, stream>>>(x, p, addp);
  gemm_kernel<<<dim3(DMODEL / BN, QLEN / BM, BATCH), dim3(256), 0, stream>>>(out);
}